// Round 4
// baseline (107.520 us; speedup 1.0000x reference)
//
#include <hip/hip_runtime.h>
#include <stdint.h>

#define BB 4
#define CC 128
#define AA 64
#define NN 4096
#define LOG2E 1.44269504088896f

using half8  = __attribute__((ext_vector_type(8))) _Float16;
using f32x4  = __attribute__((ext_vector_type(4))) float;
using f32x16 = __attribute__((ext_vector_type(16))) float;
using u32x4  = __attribute__((ext_vector_type(4))) uint32_t;

__device__ __forceinline__ float fexp2(float x) {
  float r; asm("v_exp_f32 %0, %1" : "=v"(r) : "v"(x)); return r;
}

// Fragment layouts (written by proj, read by attn as dense 1KB wave loads):
//  qfrag[b][n32][ks][lane][8]          n32 = q-row/32, a = ks*16 + (l>>5)*8 + j
//  kfrag[b][k64][mt][ks][lane][8]      key m = mt*32 + (l&31)
//  vfrag[b][m64][ms][ct][lane][8]      c = ct*32 + (l&31), m = ms*16 + (l>>5)*8 + j

// ---------------------------------------------------------------------------
// Kernel 1: projections -> fragment-order outputs. qT pre-scaled by log2e.
// ---------------------------------------------------------------------------
__global__ __launch_bounds__(256) void proj_kernel(
    const float* __restrict__ x,
    const float* __restrict__ Wq, const float* __restrict__ bq,
    const float* __restrict__ Wk, const float* __restrict__ bk,
    const float* __restrict__ Wv, const float* __restrict__ bv,
    _Float16* __restrict__ qfrag, _Float16* __restrict__ kfrag,
    _Float16* __restrict__ vfrag)
{
  __shared__ _Float16 xT[64][136];
  __shared__ _Float16 bounce[4][64][72];
  const int tid = threadIdx.x;
  const int wid = tid >> 6, lane = tid & 63;
  const int g = lane >> 4, lr = lane & 15;
  const int c32 = lane & 31, h = lane >> 5;
  const int b = blockIdx.x & 3, nt = blockIdx.x >> 2;
  const int n0 = nt * 64;

  for (int i = 0; i < 8; ++i) {
    int idx = i * 256 + tid;
    int c = idx >> 4, s = idx & 15;
    float4 xv = *(const float4*)(x + (size_t)(b * CC + c) * NN + n0 + s * 4);
    xT[s*4+0][c] = (_Float16)xv.x;
    xT[s*4+1][c] = (_Float16)xv.y;
    xT[s*4+2][c] = (_Float16)xv.z;
    xT[s*4+3][c] = (_Float16)xv.w;
  }
  __syncthreads();

  const float* Wp; const float* bp; int rbase;
  if (wid == 0)      { Wp = Wq; bp = bq; rbase = 0; }
  else if (wid == 1) { Wp = Wk; bp = bk; rbase = 0; }
  else               { Wp = Wv; bp = bv; rbase = (wid - 2) * 64; }
  const float oscale = (wid == 0) ? LOG2E : 1.0f;

  const f32x4 zero4 = {0.f, 0.f, 0.f, 0.f};
  f32x4 acc[4][4];
  #pragma unroll
  for (int i = 0; i < 4; ++i)
    #pragma unroll
    for (int j = 0; j < 4; ++j) acc[i][j] = zero4;

  #pragma unroll
  for (int ks = 0; ks < 4; ++ks) {
    half8 af[4];
    #pragma unroll
    for (int nf = 0; nf < 4; ++nf)
      af[nf] = *(const half8*)&xT[nf*16 + lr][ks*32 + g*8];
    half8 bfr[4];
    #pragma unroll
    for (int rf = 0; rf < 4; ++rf) {
      const float* wrow = Wp + (size_t)(rbase + rf*16 + lr) * CC + ks*32 + g*8;
      float4 w0 = *(const float4*)wrow;
      float4 w1 = *(const float4*)(wrow + 4);
      half8 t;
      t[0]=(_Float16)w0.x; t[1]=(_Float16)w0.y; t[2]=(_Float16)w0.z; t[3]=(_Float16)w0.w;
      t[4]=(_Float16)w1.x; t[5]=(_Float16)w1.y; t[6]=(_Float16)w1.z; t[7]=(_Float16)w1.w;
      bfr[rf] = t;
    }
    #pragma unroll
    for (int nf = 0; nf < 4; ++nf)
      #pragma unroll
      for (int rf = 0; rf < 4; ++rf)
        acc[nf][rf] = __builtin_amdgcn_mfma_f32_16x16x32_f16(af[nf], bfr[rf], acc[nf][rf], 0, 0, 0);
  }

  // bias + bounce: q/k as [n][a]; v as [c_local][m_local]
  #pragma unroll
  for (int rf = 0; rf < 4; ++rf) {
    float bias = bp[rbase + rf*16 + lr];
    #pragma unroll
    for (int nf = 0; nf < 4; ++nf)
      #pragma unroll
      for (int r = 0; r < 4; ++r) {
        float val = (acc[nf][rf][r] + bias) * oscale;
        if (wid < 2) bounce[wid][nf*16 + 4*g + r][rf*16 + lr] = (_Float16)val;
        else         bounce[wid][rf*16 + lr][nf*16 + 4*g + r] = (_Float16)val;
      }
  }
  __syncthreads();

  if (wid == 0) {
    _Float16* dst = qfrag + (size_t)(b*128 + 2*nt) * 2048;
    #pragma unroll
    for (int t = 0; t < 8; ++t) {
      int n32t = t >> 2, ks = t & 3;
      half8 v8 = *(const half8*)&bounce[0][n32t*32 + c32][ks*16 + h*8];
      *(half8*)(dst + (size_t)(n32t*4 + ks)*512 + lane*8) = v8;
    }
  } else if (wid == 1) {
    _Float16* dst = kfrag + (size_t)(b*64 + nt) * 4096;
    #pragma unroll
    for (int t = 0; t < 8; ++t) {
      int mt = t >> 2, ks = t & 3;
      half8 v8 = *(const half8*)&bounce[1][mt*32 + c32][ks*16 + h*8];
      *(half8*)(dst + (size_t)(mt*4 + ks)*512 + lane*8) = v8;
    }
  } else {
    _Float16* dst = vfrag + (size_t)(b*64 + nt) * 8192;
    #pragma unroll
    for (int t = 0; t < 8; ++t) {
      int ms = t >> 1, ctl = t & 1;
      int ct = (wid - 2)*2 + ctl;
      half8 v8 = *(const half8*)&bounce[wid][ctl*32 + c32][ms*16 + h*8];
      *(half8*)(dst + (size_t)(ms*4 + ct)*512 + lane*8) = v8;
    }
  }
}

// ---------------------------------------------------------------------------
// Kernel 2: flash attention, 32x32x16 MFMA, zero-LDS barrier-free main loop.
// Block = (b, 64 q-rows), 512 threads = 2 q-subtiles x 4 key-quarters.
// Full-iteration prefetch: V(it+1) and K(it+1) are issued during iter it,
// rotating through NAMED double-buffers with compile-time-constant indexing
// only (macro-expanded even/odd bodies — no lambda, no reference-bound
// arrays, so SROA keeps everything in registers; rule #20).
// Budget: 2 waves/SIMD -> 256 unified regs; ctx(64 AGPR) + ~160 arch fits.
// ---------------------------------------------------------------------------
__global__ __launch_bounds__(512, 2) void attn_kernel(
    const float* __restrict__ x,
    const _Float16* __restrict__ qfrag, const _Float16* __restrict__ kfrag,
    const _Float16* __restrict__ vfrag, float* __restrict__ out)
{
  // ctxb [6][4096] f32 (96K) | statb [6][64] (1.5K) | ctxw [64][132] (33.8K)
  __shared__ __align__(16) float smem_f[24576 + 384 + 8448];
  float* ctxb  = smem_f;
  float* statb = smem_f + 24576;
  float* ctxw  = smem_f + 24960;

  const int tid = threadIdx.x;
  const int wid = tid >> 6, lane = tid & 63;
  const int c32 = lane & 31;
  const int h = lane >> 5;
  const bool hb = (h != 0);
  const int sub = wid >> 2;        // q-subtile (32 rows each)
  const int qr  = wid & 3;         // key quarter (1024 keys each)
  const int b = blockIdx.x & 3, qt = blockIdx.x >> 2;   // qt 0..63
  const int n0 = qt * 64;

  // Q fragments (dense 1KB loads)
  half8 qf[4];
  const _Float16* qfb = qfrag + (size_t)(b*128 + qt*2 + sub) * 2048;
  #pragma unroll
  for (int ks = 0; ks < 4; ++ks)
    qf[ks] = *(const half8*)(qfb + ks*512 + lane*8);

  const _Float16* kfb = kfrag + (size_t)(b*64 + qr*16) * 4096;
  const _Float16* vfb = vfrag + (size_t)(b*64 + qr*16) * 8192;

  f32x16 ctx[4];
  #pragma unroll
  for (int ct = 0; ct < 4; ++ct)
    #pragma unroll
    for (int r = 0; r < 16; ++r) ctx[ct][r] = 0.f;
  float run_m = -1e30f, run_l = 0.f;

  // prologue: K tile 0 + both V batches of tile 0 into buffer set 0
  half8 kf[2][4];
  #pragma unroll
  for (int mt = 0; mt < 2; ++mt)
    #pragma unroll
    for (int ks = 0; ks < 4; ++ks)
      kf[mt][ks] = *(const half8*)(kfb + (size_t)(mt*4 + ks)*512 + lane*8);

  half8 vA0[2][4], vB0[2][4], vA1[2][4], vB1[2][4];
  #pragma unroll
  for (int ms = 0; ms < 2; ++ms)
    #pragma unroll
    for (int ct = 0; ct < 4; ++ct) {
      vA0[ms][ct] = *(const half8*)(vfb + (size_t)(ms*4 + ct)*512 + lane*8);
      vB0[ms][ct] = *(const half8*)(vfb + (size_t)((ms+2)*4 + ct)*512 + lane*8);
    }

#define ITER_BODY(IT, vAc, vBc, vAn, vBn)                                      \
  {                                                                            \
    const _Float16* vtn = vfb + (size_t)(((IT) + 1) & 15) * 8192;              \
    /* issue next-iter V batch A immediately (full-iteration distance) */      \
    _Pragma("unroll")                                                          \
    for (int ms = 0; ms < 2; ++ms)                                             \
      _Pragma("unroll")                                                        \
      for (int ct = 0; ct < 4; ++ct)                                           \
        vAn[ms][ct] = *(const half8*)(vtn + (size_t)(ms*4 + ct)*512 + lane*8); \
    /* QK^T: S^T[m][n]; col n = lane&31, row m = (r&3)+8*(r>>2)+4h (+32mt) */  \
    f32x16 s[2];                                                               \
    _Pragma("unroll")                                                          \
    for (int mt = 0; mt < 2; ++mt)                                             \
      _Pragma("unroll")                                                        \
      for (int r = 0; r < 16; ++r) s[mt][r] = 0.f;                             \
    __builtin_amdgcn_s_setprio(1);                                             \
    _Pragma("unroll")                                                          \
    for (int ks = 0; ks < 4; ++ks) {                                           \
      s[0] = __builtin_amdgcn_mfma_f32_32x32x16_f16(kf[0][ks], qf[ks], s[0], 0, 0, 0); \
      s[1] = __builtin_amdgcn_mfma_f32_32x32x16_f16(kf[1][ks], qf[ks], s[1], 0, 0, 0); \
    }                                                                          \
    __builtin_amdgcn_s_setprio(0);                                             \
    /* next-iter V batch B + next K tile: in flight across softmax + PV */     \
    _Pragma("unroll")                                                          \
    for (int ms = 0; ms < 2; ++ms)                                             \
      _Pragma("unroll")                                                        \
      for (int ct = 0; ct < 4; ++ct)                                           \
        vBn[ms][ct] = *(const half8*)(vtn + (size_t)((ms+2)*4 + ct)*512 + lane*8); \
    {                                                                          \
      const _Float16* kn = kfb + (size_t)(((IT) + 1) & 15) * 4096;             \
      _Pragma("unroll")                                                        \
      for (int mt = 0; mt < 2; ++mt)                                           \
        _Pragma("unroll")                                                      \
        for (int ks = 0; ks < 4; ++ks)                                         \
          kf[mt][ks] = *(const half8*)(kn + (size_t)(mt*4 + ks)*512 + lane*8); \
    }                                                                          \
    /* lane-local online softmax; tree max depth 5 */                          \
    float t8[8];                                                               \
    _Pragma("unroll")                                                          \
    for (int r = 0; r < 8; ++r)                                                \
      t8[r] = fmaxf(fmaxf(s[0][r], s[0][r+8]), fmaxf(s[1][r], s[1][r+8]));     \
    _Pragma("unroll")                                                          \
    for (int off = 4; off > 0; off >>= 1)                                      \
      _Pragma("unroll")                                                        \
      for (int r = 0; r < off; ++r) t8[r] = fmaxf(t8[r], t8[r+off]);           \
    float tm = t8[0];                                                          \
    float tmf = fmaxf(tm, __shfl_xor(tm, 32));                                 \
    if (!__all(tmf <= run_m + 8.f)) {                                          \
      float nm = fmaxf(run_m, tmf);                                            \
      float corr = fexp2(run_m - nm);                                          \
      run_m = nm;                                                              \
      run_l *= corr;                                                           \
      float cr[16];                                                            \
      _Pragma("unroll")                                                        \
      for (int r = 0; r < 16; ++r) {                                           \
        int nr = (r & 3) + 8*(r >> 2) + 4*h;                                   \
        cr[r] = __shfl(corr, nr);                                              \
      }                                                                        \
      _Pragma("unroll")                                                        \
      for (int ct = 0; ct < 4; ++ct)                                           \
        _Pragma("unroll")                                                      \
        for (int r = 0; r < 16; ++r) ctx[ct][r] *= cr[r];                      \
    }                                                                          \
    /* exp + pack fp16 + half-exchange via shfl_xor(32) -> PV A-frags */       \
    float rs = 0.f;                                                            \
    half8 pa4[4];                                                              \
    _Pragma("unroll")                                                          \
    for (int mt = 0; mt < 2; ++mt) {                                           \
      uint32_t u[8];                                                           \
      _Pragma("unroll")                                                        \
      for (int i = 0; i < 8; ++i) {                                            \
        float pa_ = fexp2(s[mt][2*i]   - run_m);                               \
        float pb_ = fexp2(s[mt][2*i+1] - run_m);                               \
        rs += pa_ + pb_;                                                       \
        u[i] = __builtin_bit_cast(uint32_t, __builtin_amdgcn_cvt_pkrtz(pa_, pb_)); \
      }                                                                        \
      uint32_t t02 = __shfl_xor(hb ? u[0] : u[2], 32);                         \
      uint32_t t13 = __shfl_xor(hb ? u[1] : u[3], 32);                         \
      uint32_t t46 = __shfl_xor(hb ? u[4] : u[6], 32);                         \
      uint32_t t57 = __shfl_xor(hb ? u[5] : u[7], 32);                         \
      u32x4 w0 = { hb ? t02 : u[0], hb ? t13 : u[1],                           \
                   hb ? u[2] : t02, hb ? u[3] : t13 };                         \
      u32x4 w1 = { hb ? t46 : u[4], hb ? t57 : u[5],                           \
                   hb ? u[6] : t46, hb ? u[7] : t57 };                         \
      pa4[2*mt]   = __builtin_bit_cast(half8, w0);                             \
      pa4[2*mt+1] = __builtin_bit_cast(half8, w1);                             \
    }                                                                          \
    rs += __shfl_xor(rs, 32);                                                  \
    run_l += rs;                                                               \
    /* PV: ctx[n][c] += P[n][m] V[m][c]  (V from previous-iter prefetch) */    \
    __builtin_amdgcn_s_setprio(1);                                             \
    _Pragma("unroll")                                                          \
    for (int ms = 0; ms < 2; ++ms)                                             \
      _Pragma("unroll")                                                        \
      for (int ct = 0; ct < 4; ++ct)                                           \
        ctx[ct] = __builtin_amdgcn_mfma_f32_32x32x16_f16(pa4[ms], vAc[ms][ct], ctx[ct], 0, 0, 0); \
    _Pragma("unroll")                                                          \
    for (int ms = 0; ms < 2; ++ms)                                             \
      _Pragma("unroll")                                                        \
      for (int ct = 0; ct < 4; ++ct)                                           \
        ctx[ct] = __builtin_amdgcn_mfma_f32_32x32x16_f16(pa4[ms+2], vBc[ms][ct], ctx[ct], 0, 0, 0); \
    __builtin_amdgcn_s_setprio(0);                                             \
  }

  #pragma unroll 1
  for (int itt = 0; itt < 16; itt += 2) {
    ITER_BODY(itt,     vA0, vB0, vA1, vB1)
    ITER_BODY(itt + 1, vA1, vB1, vA0, vB0)
  }
#undef ITER_BODY

  // ---- 4-way key merge per q-subtile (only synchronization in the kernel)
  if (qr != 0) {
    const int slot = sub*3 + (qr - 1);
    #pragma unroll
    for (int ct = 0; ct < 4; ++ct)
      #pragma unroll
      for (int r = 0; r < 16; ++r)
        ctxb[slot*4096 + (ct*16 + r)*64 + lane] = ctx[ct][r];
    if (h == 0) {
      statb[slot*64 + c32*2 + 0] = run_m;
      statb[slot*64 + c32*2 + 1] = run_l;
    }
  }
  __syncthreads();

  if (qr == 0) {
    float m_w[4], l_w[4];
    m_w[0] = run_m; l_w[0] = run_l;
    #pragma unroll
    for (int w = 1; w < 4; ++w) {
      const int slot = sub*3 + (w - 1);
      m_w[w] = statb[slot*64 + c32*2 + 0];
      l_w[w] = statb[slot*64 + c32*2 + 1];
    }
    float M = fmaxf(fmaxf(m_w[0], m_w[1]), fmaxf(m_w[2], m_w[3]));
    float sc[4], L = 0.f;
    #pragma unroll
    for (int w = 0; w < 4; ++w) { sc[w] = fexp2(m_w[w] - M); L += l_w[w]*sc[w]; }
    float inv = 1.0f / L;
    float a0[16], a1[16], a2[16], a3[16], ai[16];
    #pragma unroll
    for (int r = 0; r < 16; ++r) {
      int nr = (r & 3) + 8*(r >> 2) + 4*h;
      a0[r] = __shfl(sc[0], nr); a1[r] = __shfl(sc[1], nr);
      a2[r] = __shfl(sc[2], nr); a3[r] = __shfl(sc[3], nr);
      ai[r] = __shfl(inv, nr);
    }
    #pragma unroll
    for (int ct = 0; ct < 4; ++ct)
      #pragma unroll
      for (int r = 0; r < 16; ++r) {
        int nr = (r & 3) + 8*(r >> 2) + 4*h;
        float vmrg = ctx[ct][r]*a0[r]
                   + ctxb[(sub*3 + 0)*4096 + (ct*16 + r)*64 + lane]*a1[r]
                   + ctxb[(sub*3 + 1)*4096 + (ct*16 + r)*64 + lane]*a2[r]
                   + ctxb[(sub*3 + 2)*4096 + (ct*16 + r)*64 + lane]*a3[r];
        ctxw[(sub*32 + nr)*132 + ct*32 + c32] = vmrg * ai[r];
      }
  }
  __syncthreads();

  // ---- residual add + store: thread t -> channel c = t>>2, 16 n each
  {
    const int c  = tid >> 2;
    const int nl = (tid & 3) * 16;
    const float* xr   = x   + (size_t)(b*CC + c)*NN + n0 + nl;
    float*       orow = out + (size_t)(b*CC + c)*NN + n0 + nl;
    #pragma unroll
    for (int i4 = 0; i4 < 4; ++i4) {
      float4 xv = *(const float4*)(xr + i4*4);
      float4 o;
      o.x = xv.x + ctxw[(nl + i4*4 + 0)*132 + c];
      o.y = xv.y + ctxw[(nl + i4*4 + 1)*132 + c];
      o.z = xv.z + ctxw[(nl + i4*4 + 2)*132 + c];
      o.w = xv.w + ctxw[(nl + i4*4 + 3)*132 + c];
      *(float4*)(orow + i4*4) = o;
    }
  }
}

// ---------------------------------------------------------------------------
extern "C" void kernel_launch(void* const* d_in, const int* in_sizes, int n_in,
                              void* d_out, int out_size, void* d_ws, size_t ws_size,
                              hipStream_t stream) {
  const float* x  = (const float*)d_in[0];
  const float* Wq = (const float*)d_in[1];
  const float* bq = (const float*)d_in[2];
  const float* Wk = (const float*)d_in[3];
  const float* bk = (const float*)d_in[4];
  const float* Wv = (const float*)d_in[5];
  const float* bv = (const float*)d_in[6];
  float* out = (float*)d_out;

  _Float16* qfrag = (_Float16*)d_ws;                       // 2MB
  _Float16* kfrag = qfrag + (size_t)BB * 128 * 2048;       // 2MB
  _Float16* vfrag = kfrag + (size_t)BB * 64 * 4096;        // 4MB

  proj_kernel<<<dim3(BB * (NN/64)), dim3(256), 0, stream>>>(
      x, Wq, bq, Wk, bk, Wv, bv, qfrag, kfrag, vfrag);
  attn_kernel<<<dim3(BB * (NN/64)), dim3(512), 0, stream>>>(
      x, qfrag, kfrag, vfrag, out);
}

// Round 5
// 61.666 us; speedup vs baseline: 1.7436x; 1.7436x over previous
//
#include <hip/hip_runtime.h>
#include <stdint.h>

#define BB 4
#define CC 128
#define AA 64
#define NN 4096
#define LOG2E 1.44269504088896f

using half8  = __attribute__((ext_vector_type(8))) _Float16;
using f32x4  = __attribute__((ext_vector_type(4))) float;
using f32x16 = __attribute__((ext_vector_type(16))) float;
using u32x4  = __attribute__((ext_vector_type(4))) uint32_t;

__device__ __forceinline__ float fexp2(float x) {
  float r; asm("v_exp_f32 %0, %1" : "=v"(r) : "v"(x)); return r;
}

// async 16B-per-lane global -> LDS copy (wave-uniform LDS base + lane*16;
// per-lane global src). Zero VGPR cost for the staged data.
__device__ __forceinline__ void gload_lds16(const void* g, void* l) {
  __builtin_amdgcn_global_load_lds(
      (const __attribute__((address_space(1))) uint32_t*)g,
      (__attribute__((address_space(3))) uint32_t*)l, 16, 0, 0);
}

// Fragment layouts (written by proj, read by attn as dense 1KB wave loads):
//  qfrag[b][n32][ks][lane][8]          n32 = q-row/32, a = ks*16 + (l>>5)*8 + j
//  kfrag[b][k64][mt][ks][lane][8]      key m = mt*32 + (l&31)
//  vfrag[b][m64][ms][ct][lane][8]      c = ct*32 + (l&31), m = ms*16 + (l>>5)*8 + j

// ---------------------------------------------------------------------------
// Kernel 1: projections -> fragment-order outputs. qT pre-scaled by log2e.
// ---------------------------------------------------------------------------
__global__ __launch_bounds__(256) void proj_kernel(
    const float* __restrict__ x,
    const float* __restrict__ Wq, const float* __restrict__ bq,
    const float* __restrict__ Wk, const float* __restrict__ bk,
    const float* __restrict__ Wv, const float* __restrict__ bv,
    _Float16* __restrict__ qfrag, _Float16* __restrict__ kfrag,
    _Float16* __restrict__ vfrag)
{
  __shared__ _Float16 xT[64][136];
  __shared__ _Float16 bounce[4][64][72];
  const int tid = threadIdx.x;
  const int wid = tid >> 6, lane = tid & 63;
  const int g = lane >> 4, lr = lane & 15;
  const int c32 = lane & 31, h = lane >> 5;
  const int b = blockIdx.x & 3, nt = blockIdx.x >> 2;
  const int n0 = nt * 64;

  for (int i = 0; i < 8; ++i) {
    int idx = i * 256 + tid;
    int c = idx >> 4, s = idx & 15;
    float4 xv = *(const float4*)(x + (size_t)(b * CC + c) * NN + n0 + s * 4);
    xT[s*4+0][c] = (_Float16)xv.x;
    xT[s*4+1][c] = (_Float16)xv.y;
    xT[s*4+2][c] = (_Float16)xv.z;
    xT[s*4+3][c] = (_Float16)xv.w;
  }
  __syncthreads();

  const float* Wp; const float* bp; int rbase;
  if (wid == 0)      { Wp = Wq; bp = bq; rbase = 0; }
  else if (wid == 1) { Wp = Wk; bp = bk; rbase = 0; }
  else               { Wp = Wv; bp = bv; rbase = (wid - 2) * 64; }
  const float oscale = (wid == 0) ? LOG2E : 1.0f;

  const f32x4 zero4 = {0.f, 0.f, 0.f, 0.f};
  f32x4 acc[4][4];
  #pragma unroll
  for (int i = 0; i < 4; ++i)
    #pragma unroll
    for (int j = 0; j < 4; ++j) acc[i][j] = zero4;

  #pragma unroll
  for (int ks = 0; ks < 4; ++ks) {
    half8 af[4];
    #pragma unroll
    for (int nf = 0; nf < 4; ++nf)
      af[nf] = *(const half8*)&xT[nf*16 + lr][ks*32 + g*8];
    half8 bfr[4];
    #pragma unroll
    for (int rf = 0; rf < 4; ++rf) {
      const float* wrow = Wp + (size_t)(rbase + rf*16 + lr) * CC + ks*32 + g*8;
      float4 w0 = *(const float4*)wrow;
      float4 w1 = *(const float4*)(wrow + 4);
      half8 t;
      t[0]=(_Float16)w0.x; t[1]=(_Float16)w0.y; t[2]=(_Float16)w0.z; t[3]=(_Float16)w0.w;
      t[4]=(_Float16)w1.x; t[5]=(_Float16)w1.y; t[6]=(_Float16)w1.z; t[7]=(_Float16)w1.w;
      bfr[rf] = t;
    }
    #pragma unroll
    for (int nf = 0; nf < 4; ++nf)
      #pragma unroll
      for (int rf = 0; rf < 4; ++rf)
        acc[nf][rf] = __builtin_amdgcn_mfma_f32_16x16x32_f16(af[nf], bfr[rf], acc[nf][rf], 0, 0, 0);
  }

  // bias + bounce: q/k as [n][a]; v as [c_local][m_local]
  #pragma unroll
  for (int rf = 0; rf < 4; ++rf) {
    float bias = bp[rbase + rf*16 + lr];
    #pragma unroll
    for (int nf = 0; nf < 4; ++nf)
      #pragma unroll
      for (int r = 0; r < 4; ++r) {
        float val = (acc[nf][rf][r] + bias) * oscale;
        if (wid < 2) bounce[wid][nf*16 + 4*g + r][rf*16 + lr] = (_Float16)val;
        else         bounce[wid][rf*16 + lr][nf*16 + 4*g + r] = (_Float16)val;
      }
  }
  __syncthreads();

  if (wid == 0) {
    _Float16* dst = qfrag + (size_t)(b*128 + 2*nt) * 2048;
    #pragma unroll
    for (int t = 0; t < 8; ++t) {
      int n32t = t >> 2, ks = t & 3;
      half8 v8 = *(const half8*)&bounce[0][n32t*32 + c32][ks*16 + h*8];
      *(half8*)(dst + (size_t)(n32t*4 + ks)*512 + lane*8) = v8;
    }
  } else if (wid == 1) {
    _Float16* dst = kfrag + (size_t)(b*64 + nt) * 4096;
    #pragma unroll
    for (int t = 0; t < 8; ++t) {
      int mt = t >> 2, ks = t & 3;
      half8 v8 = *(const half8*)&bounce[1][mt*32 + c32][ks*16 + h*8];
      *(half8*)(dst + (size_t)(mt*4 + ks)*512 + lane*8) = v8;
    }
  } else {
    _Float16* dst = vfrag + (size_t)(b*64 + nt) * 8192;
    #pragma unroll
    for (int t = 0; t < 8; ++t) {
      int ms = t >> 1, ctl = t & 1;
      int ct = (wid - 2)*2 + ctl;
      half8 v8 = *(const half8*)&bounce[wid][ctl*32 + c32][ms*16 + h*8];
      *(half8*)(dst + (size_t)(ms*4 + ct)*512 + lane*8) = v8;
    }
  }
}

// ---------------------------------------------------------------------------
// Kernel 2: flash attention, 32x32x16 MFMA.
// Block = (b, 64 q-rows), 512 threads = 2 q-subtiles x 4 key-quarters.
// 2-phase async pipeline: V tile (it+1) is DMA'd global->LDS (zero VGPR cost)
// at the top of iter it; one __syncthreads per iter (its vmcnt(0) drain is
// the arrival guarantee). The sub0/sub1 pair shares each qr's V buffer and
// each stages half. K stays in the register double-rotate (full-iter
// distance). V is consumed via ds_read_b128 in two 8-frag batches.
// Merge buffers overlay the V staging LDS (only used after final barrier).
// ---------------------------------------------------------------------------
__global__ __launch_bounds__(512, 2) void attn_kernel(
    const float* __restrict__ x,
    const _Float16* __restrict__ qfrag, const _Float16* __restrict__ kfrag,
    const _Float16* __restrict__ vfrag, float* __restrict__ out)
{
  // Union: main loop -> vstage[4 qr][2 buf][16KB] = 128KB
  //        epilogue  -> ctxb [6][4096] f32 (96K) | statb (1.5K) | ctxw (33.8K)
  __shared__ __align__(16) float smem_f[24576 + 384 + 8448];   // 133,632 B
  float* ctxb  = smem_f;
  float* statb = smem_f + 24576;
  float* ctxw  = smem_f + 24960;
  char*  vstage = (char*)smem_f;                                // [0,131072)

  const int tid = threadIdx.x;
  const int wid = tid >> 6, lane = tid & 63;
  const int c32 = lane & 31;
  const int h = lane >> 5;
  const bool hb = (h != 0);
  const int sub = wid >> 2;        // q-subtile (32 rows each)
  const int qr  = wid & 3;         // key quarter (1024 keys each)
  const int b = blockIdx.x & 3, qt = blockIdx.x >> 2;   // qt 0..63
  const int n0 = qt * 64;

  // Q fragments (dense 1KB loads)
  half8 qf[4];
  const _Float16* qfb = qfrag + (size_t)(b*128 + qt*2 + sub) * 2048;
  #pragma unroll
  for (int ks = 0; ks < 4; ++ks)
    qf[ks] = *(const half8*)(qfb + ks*512 + lane*8);

  const _Float16* kfb = kfrag + (size_t)(b*64 + qr*16) * 4096;
  const _Float16* vfb = vfrag + (size_t)(b*64 + qr*16) * 8192;

  f32x16 ctx[4];
  #pragma unroll
  for (int ct = 0; ct < 4; ++ct)
    #pragma unroll
    for (int r = 0; r < 16; ++r) ctx[ct][r] = 0.f;
  float run_m = -1e30f, run_l = 0.f;

  // prologue: K tile 0 into regs; V tile 0 DMA'd into LDS buf 0
  half8 kf[2][4];
  #pragma unroll
  for (int mt = 0; mt < 2; ++mt)
    #pragma unroll
    for (int ks = 0; ks < 4; ++ks)
      kf[mt][ks] = *(const half8*)(kfb + (size_t)(mt*4 + ks)*512 + lane*8);

  {
    const _Float16* vsrc = vfb + sub*4096;
    char* vdst = vstage + ((size_t)qr*2 + 0)*16384 + sub*8192;
    #pragma unroll
    for (int i = 0; i < 8; ++i)
      gload_lds16(vsrc + i*512 + lane*8, vdst + i*1024);
  }
  __syncthreads();   // drains vmcnt: tile 0 (and qf/kf) resident

  #pragma unroll 1
  for (int it = 0; it < 16; ++it) {
    // ---- stage V(it+1) into the other buffer (DMA, no registers)
    if (it < 15) {
      const _Float16* vsrc = vfb + (size_t)(it + 1)*8192 + sub*4096;
      char* vdst = vstage + ((size_t)qr*2 + ((it + 1) & 1))*16384 + sub*8192;
      #pragma unroll
      for (int i = 0; i < 8; ++i)
        gload_lds16(vsrc + i*512 + lane*8, vdst + i*1024);
    }

    // ---- QK^T: S^T[m][n]; col n = lane&31, row m = (r&3)+8*(r>>2)+4h (+32mt)
    f32x16 s[2];
    #pragma unroll
    for (int mt = 0; mt < 2; ++mt)
      #pragma unroll
      for (int r = 0; r < 16; ++r) s[mt][r] = 0.f;
    __builtin_amdgcn_s_setprio(1);
    #pragma unroll
    for (int ks = 0; ks < 4; ++ks) {
      s[0] = __builtin_amdgcn_mfma_f32_32x32x16_f16(kf[0][ks], qf[ks], s[0], 0, 0, 0);
      s[1] = __builtin_amdgcn_mfma_f32_32x32x16_f16(kf[1][ks], qf[ks], s[1], 0, 0, 0);
    }
    __builtin_amdgcn_s_setprio(0);

    // ---- V batch A from LDS (current tile; arrival guaranteed last barrier)
    const char* vrd = vstage + ((size_t)qr*2 + (it & 1))*16384;
    half8 vA[2][4];
    #pragma unroll
    for (int ms = 0; ms < 2; ++ms)
      #pragma unroll
      for (int ct = 0; ct < 4; ++ct)
        vA[ms][ct] = *(const half8*)(vrd + (ms*4 + ct)*1024 + lane*16);

    // ---- K(it+1) into regs: full-iteration issue->use distance
    {
      const _Float16* kn = kfb + (size_t)((it + 1) & 15) * 4096;
      #pragma unroll
      for (int mt = 0; mt < 2; ++mt)
        #pragma unroll
        for (int ks = 0; ks < 4; ++ks)
          kf[mt][ks] = *(const half8*)(kn + (size_t)(mt*4 + ks)*512 + lane*8);
    }

    // ---- lane-local online softmax (column n = lane&31; partner = lane^32)
    float t8[8];
    #pragma unroll
    for (int r = 0; r < 8; ++r)
      t8[r] = fmaxf(fmaxf(s[0][r], s[0][r+8]), fmaxf(s[1][r], s[1][r+8]));
    #pragma unroll
    for (int off = 4; off > 0; off >>= 1)
      #pragma unroll
      for (int r = 0; r < off; ++r) t8[r] = fmaxf(t8[r], t8[r+off]);
    float tm = t8[0];
    float tmf = fmaxf(tm, __shfl_xor(tm, 32));
    if (!__all(tmf <= run_m + 8.f)) {
      float nm = fmaxf(run_m, tmf);
      float corr = fexp2(run_m - nm);
      run_m = nm;
      run_l *= corr;
      float cr[16];
      #pragma unroll
      for (int r = 0; r < 16; ++r) {
        int nr = (r & 3) + 8*(r >> 2) + 4*h;
        cr[r] = __shfl(corr, nr);
      }
      #pragma unroll
      for (int ct = 0; ct < 4; ++ct)
        #pragma unroll
        for (int r = 0; r < 16; ++r) ctx[ct][r] *= cr[r];
    }

    // ---- exp + pack fp16 + half-exchange via shfl_xor(32) -> PV A-frags
    float rs = 0.f;
    half8 pa4[4];
    #pragma unroll
    for (int mt = 0; mt < 2; ++mt) {
      uint32_t u[8];
      #pragma unroll
      for (int i = 0; i < 8; ++i) {
        float pa_ = fexp2(s[mt][2*i]   - run_m);
        float pb_ = fexp2(s[mt][2*i+1] - run_m);
        rs += pa_ + pb_;
        u[i] = __builtin_bit_cast(uint32_t, __builtin_amdgcn_cvt_pkrtz(pa_, pb_));
      }
      uint32_t t02 = __shfl_xor(hb ? u[0] : u[2], 32);
      uint32_t t13 = __shfl_xor(hb ? u[1] : u[3], 32);
      uint32_t t46 = __shfl_xor(hb ? u[4] : u[6], 32);
      uint32_t t57 = __shfl_xor(hb ? u[5] : u[7], 32);
      u32x4 w0 = { hb ? t02 : u[0], hb ? t13 : u[1],
                   hb ? u[2] : t02, hb ? u[3] : t13 };   // ms = 2*mt
      u32x4 w1 = { hb ? t46 : u[4], hb ? t57 : u[5],
                   hb ? u[6] : t46, hb ? u[7] : t57 };   // ms = 2*mt+1
      pa4[2*mt]   = __builtin_bit_cast(half8, w0);
      pa4[2*mt+1] = __builtin_bit_cast(half8, w1);
    }
    rs += __shfl_xor(rs, 32);
    run_l += rs;

    // ---- V batch B from LDS (covered by PV-A duration)
    half8 vB[2][4];
    #pragma unroll
    for (int ms = 0; ms < 2; ++ms)
      #pragma unroll
      for (int ct = 0; ct < 4; ++ct)
        vB[ms][ct] = *(const half8*)(vrd + ((ms + 2)*4 + ct)*1024 + lane*16);

    // ---- PV: ctx[n][c] += P[n][m] V[m][c]
    __builtin_amdgcn_s_setprio(1);
    #pragma unroll
    for (int ms = 0; ms < 2; ++ms)
      #pragma unroll
      for (int ct = 0; ct < 4; ++ct)
        ctx[ct] = __builtin_amdgcn_mfma_f32_32x32x16_f16(pa4[ms], vA[ms][ct], ctx[ct], 0, 0, 0);
    #pragma unroll
    for (int ms = 0; ms < 2; ++ms)
      #pragma unroll
      for (int ct = 0; ct < 4; ++ct)
        ctx[ct] = __builtin_amdgcn_mfma_f32_32x32x16_f16(pa4[ms+2], vB[ms][ct], ctx[ct], 0, 0, 0);
    __builtin_amdgcn_s_setprio(0);

    // ---- buffer handoff: next tile's DMA drained; all reads of buf done
    __syncthreads();
  }

  // ---- 4-way key merge per q-subtile (vstage dead after final barrier)
  if (qr != 0) {
    const int slot = sub*3 + (qr - 1);
    #pragma unroll
    for (int ct = 0; ct < 4; ++ct)
      #pragma unroll
      for (int r = 0; r < 16; ++r)
        ctxb[slot*4096 + (ct*16 + r)*64 + lane] = ctx[ct][r];
    if (h == 0) {
      statb[slot*64 + c32*2 + 0] = run_m;
      statb[slot*64 + c32*2 + 1] = run_l;
    }
  }
  __syncthreads();

  if (qr == 0) {
    float m_w[4], l_w[4];
    m_w[0] = run_m; l_w[0] = run_l;
    #pragma unroll
    for (int w = 1; w < 4; ++w) {
      const int slot = sub*3 + (w - 1);
      m_w[w] = statb[slot*64 + c32*2 + 0];
      l_w[w] = statb[slot*64 + c32*2 + 1];
    }
    float M = fmaxf(fmaxf(m_w[0], m_w[1]), fmaxf(m_w[2], m_w[3]));
    float sc[4], L = 0.f;
    #pragma unroll
    for (int w = 0; w < 4; ++w) { sc[w] = fexp2(m_w[w] - M); L += l_w[w]*sc[w]; }
    float inv = 1.0f / L;
    float a0[16], a1[16], a2[16], a3[16], ai[16];
    #pragma unroll
    for (int r = 0; r < 16; ++r) {
      int nr = (r & 3) + 8*(r >> 2) + 4*h;
      a0[r] = __shfl(sc[0], nr); a1[r] = __shfl(sc[1], nr);
      a2[r] = __shfl(sc[2], nr); a3[r] = __shfl(sc[3], nr);
      ai[r] = __shfl(inv, nr);
    }
    #pragma unroll
    for (int ct = 0; ct < 4; ++ct)
      #pragma unroll
      for (int r = 0; r < 16; ++r) {
        int nr = (r & 3) + 8*(r >> 2) + 4*h;
        float vmrg = ctx[ct][r]*a0[r]
                   + ctxb[(sub*3 + 0)*4096 + (ct*16 + r)*64 + lane]*a1[r]
                   + ctxb[(sub*3 + 1)*4096 + (ct*16 + r)*64 + lane]*a2[r]
                   + ctxb[(sub*3 + 2)*4096 + (ct*16 + r)*64 + lane]*a3[r];
        ctxw[(sub*32 + nr)*132 + ct*32 + c32] = vmrg * ai[r];
      }
  }
  __syncthreads();

  // ---- residual add + store: thread t -> channel c = t>>2, 16 n each
  {
    const int c  = tid >> 2;
    const int nl = (tid & 3) * 16;
    const float* xr   = x   + (size_t)(b*CC + c)*NN + n0 + nl;
    float*       orow = out + (size_t)(b*CC + c)*NN + n0 + nl;
    #pragma unroll
    for (int i4 = 0; i4 < 4; ++i4) {
      float4 xv = *(const float4*)(xr + i4*4);
      float4 o;
      o.x = xv.x + ctxw[(nl + i4*4 + 0)*132 + c];
      o.y = xv.y + ctxw[(nl + i4*4 + 1)*132 + c];
      o.z = xv.z + ctxw[(nl + i4*4 + 2)*132 + c];
      o.w = xv.w + ctxw[(nl + i4*4 + 3)*132 + c];
      *(float4*)(orow + i4*4) = o;
    }
  }
}

// ---------------------------------------------------------------------------
extern "C" void kernel_launch(void* const* d_in, const int* in_sizes, int n_in,
                              void* d_out, int out_size, void* d_ws, size_t ws_size,
                              hipStream_t stream) {
  const float* x  = (const float*)d_in[0];
  const float* Wq = (const float*)d_in[1];
  const float* bq = (const float*)d_in[2];
  const float* Wk = (const float*)d_in[3];
  const float* bk = (const float*)d_in[4];
  const float* Wv = (const float*)d_in[5];
  const float* bv = (const float*)d_in[6];
  float* out = (float*)d_out;

  _Float16* qfrag = (_Float16*)d_ws;                       // 2MB
  _Float16* kfrag = qfrag + (size_t)BB * 128 * 2048;       // 2MB
  _Float16* vfrag = kfrag + (size_t)BB * 64 * 4096;        // 4MB

  proj_kernel<<<dim3(BB * (NN/64)), dim3(256), 0, stream>>>(
      x, Wq, bq, Wk, bk, Wv, bv, qfrag, kfrag, vfrag);
  attn_kernel<<<dim3(BB * (NN/64)), dim3(512), 0, stream>>>(
      x, qfrag, kfrag, vfrag, out);
}

// Round 6
// 61.020 us; speedup vs baseline: 1.7620x; 1.0106x over previous
//
#include <hip/hip_runtime.h>
#include <stdint.h>

#define BB 4
#define CC 128
#define AA 64
#define NN 4096
#define LOG2E 1.44269504088896f

using half8  = __attribute__((ext_vector_type(8))) _Float16;
using f32x4  = __attribute__((ext_vector_type(4))) float;
using f32x16 = __attribute__((ext_vector_type(16))) float;
using u32x4  = __attribute__((ext_vector_type(4))) uint32_t;

__device__ __forceinline__ float fexp2(float x) {
  float r; asm("v_exp_f32 %0, %1" : "=v"(r) : "v"(x)); return r;
}

// Fragment layouts (written by proj, read by attn as dense 1KB wave loads):
//  qfrag[b][n32][ks][lane][8]          n32 = q-row/32, a = ks*16 + (l>>5)*8 + j
//  kfrag[b][k64][mt][ks][lane][8]      key m = mt*32 + (l&31)
//  vfrag[b][m64][ms][ct][lane][8]      c = ct*32 + (l&31), m = ms*16 + (l>>5)*8 + j

// ---------------------------------------------------------------------------
// Kernel 1: projections -> fragment-order outputs. qT pre-scaled by log2e.
// ---------------------------------------------------------------------------
__global__ __launch_bounds__(256) void proj_kernel(
    const float* __restrict__ x,
    const float* __restrict__ Wq, const float* __restrict__ bq,
    const float* __restrict__ Wk, const float* __restrict__ bk,
    const float* __restrict__ Wv, const float* __restrict__ bv,
    _Float16* __restrict__ qfrag, _Float16* __restrict__ kfrag,
    _Float16* __restrict__ vfrag)
{
  __shared__ _Float16 xT[64][136];
  __shared__ _Float16 bounce[4][64][72];
  const int tid = threadIdx.x;
  const int wid = tid >> 6, lane = tid & 63;
  const int g = lane >> 4, lr = lane & 15;
  const int c32 = lane & 31, h = lane >> 5;
  const int b = blockIdx.x & 3, nt = blockIdx.x >> 2;
  const int n0 = nt * 64;

  for (int i = 0; i < 8; ++i) {
    int idx = i * 256 + tid;
    int c = idx >> 4, s = idx & 15;
    float4 xv = *(const float4*)(x + (size_t)(b * CC + c) * NN + n0 + s * 4);
    xT[s*4+0][c] = (_Float16)xv.x;
    xT[s*4+1][c] = (_Float16)xv.y;
    xT[s*4+2][c] = (_Float16)xv.z;
    xT[s*4+3][c] = (_Float16)xv.w;
  }
  __syncthreads();

  const float* Wp; const float* bp; int rbase;
  if (wid == 0)      { Wp = Wq; bp = bq; rbase = 0; }
  else if (wid == 1) { Wp = Wk; bp = bk; rbase = 0; }
  else               { Wp = Wv; bp = bv; rbase = (wid - 2) * 64; }
  const float oscale = (wid == 0) ? LOG2E : 1.0f;

  const f32x4 zero4 = {0.f, 0.f, 0.f, 0.f};
  f32x4 acc[4][4];
  #pragma unroll
  for (int i = 0; i < 4; ++i)
    #pragma unroll
    for (int j = 0; j < 4; ++j) acc[i][j] = zero4;

  #pragma unroll
  for (int ks = 0; ks < 4; ++ks) {
    half8 af[4];
    #pragma unroll
    for (int nf = 0; nf < 4; ++nf)
      af[nf] = *(const half8*)&xT[nf*16 + lr][ks*32 + g*8];
    half8 bfr[4];
    #pragma unroll
    for (int rf = 0; rf < 4; ++rf) {
      const float* wrow = Wp + (size_t)(rbase + rf*16 + lr) * CC + ks*32 + g*8;
      float4 w0 = *(const float4*)wrow;
      float4 w1 = *(const float4*)(wrow + 4);
      half8 t;
      t[0]=(_Float16)w0.x; t[1]=(_Float16)w0.y; t[2]=(_Float16)w0.z; t[3]=(_Float16)w0.w;
      t[4]=(_Float16)w1.x; t[5]=(_Float16)w1.y; t[6]=(_Float16)w1.z; t[7]=(_Float16)w1.w;
      bfr[rf] = t;
    }
    #pragma unroll
    for (int nf = 0; nf < 4; ++nf)
      #pragma unroll
      for (int rf = 0; rf < 4; ++rf)
        acc[nf][rf] = __builtin_amdgcn_mfma_f32_16x16x32_f16(af[nf], bfr[rf], acc[nf][rf], 0, 0, 0);
  }

  // bias + bounce: q/k as [n][a]; v as [c_local][m_local]
  #pragma unroll
  for (int rf = 0; rf < 4; ++rf) {
    float bias = bp[rbase + rf*16 + lr];
    #pragma unroll
    for (int nf = 0; nf < 4; ++nf)
      #pragma unroll
      for (int r = 0; r < 4; ++r) {
        float val = (acc[nf][rf][r] + bias) * oscale;
        if (wid < 2) bounce[wid][nf*16 + 4*g + r][rf*16 + lr] = (_Float16)val;
        else         bounce[wid][rf*16 + lr][nf*16 + 4*g + r] = (_Float16)val;
      }
  }
  __syncthreads();

  if (wid == 0) {
    _Float16* dst = qfrag + (size_t)(b*128 + 2*nt) * 2048;
    #pragma unroll
    for (int t = 0; t < 8; ++t) {
      int n32t = t >> 2, ks = t & 3;
      half8 v8 = *(const half8*)&bounce[0][n32t*32 + c32][ks*16 + h*8];
      *(half8*)(dst + (size_t)(n32t*4 + ks)*512 + lane*8) = v8;
    }
  } else if (wid == 1) {
    _Float16* dst = kfrag + (size_t)(b*64 + nt) * 4096;
    #pragma unroll
    for (int t = 0; t < 8; ++t) {
      int mt = t >> 2, ks = t & 3;
      half8 v8 = *(const half8*)&bounce[1][mt*32 + c32][ks*16 + h*8];
      *(half8*)(dst + (size_t)(mt*4 + ks)*512 + lane*8) = v8;
    }
  } else {
    _Float16* dst = vfrag + (size_t)(b*64 + nt) * 8192;
    #pragma unroll
    for (int t = 0; t < 8; ++t) {
      int ms = t >> 1, ctl = t & 1;
      int ct = (wid - 2)*2 + ctl;
      half8 v8 = *(const half8*)&bounce[wid][ctl*32 + c32][ms*16 + h*8];
      *(half8*)(dst + (size_t)(ms*4 + ct)*512 + lane*8) = v8;
    }
  }
}

// ---------------------------------------------------------------------------
// Kernel 2: flash attention, 32x32x16 MFMA, zero-LDS barrier-free main loop.
// Block = (b, 64 q-rows), 512 threads = 2 q-subtiles x 4 key-quarters.
// Phase-rotated software pipeline (no new buffers, all in-place single-set):
//   softmax(it) -> QK^T(it+1) -> K(it+2) issue -> PV(it) -> V(it+1) issue
// This merges QK^T+PV into one MFMA burst (other wave's VALU fills it),
// overlaps the pack tail with QK^T, and gives every load a full-iteration
// issue->use distance. Register set identical to the 53.4us baseline.
// ---------------------------------------------------------------------------
__global__ __launch_bounds__(512, 2) void attn_kernel(
    const float* __restrict__ x,
    const _Float16* __restrict__ qfrag, const _Float16* __restrict__ kfrag,
    const _Float16* __restrict__ vfrag, float* __restrict__ out)
{
  // ctxb [6][4096] f32 (96K) | statb [6][64] (1.5K) | ctxw [64][132] (33.8K)
  __shared__ __align__(16) float smem_f[24576 + 384 + 8448];
  float* ctxb  = smem_f;
  float* statb = smem_f + 24576;
  float* ctxw  = smem_f + 24960;

  const int tid = threadIdx.x;
  const int wid = tid >> 6, lane = tid & 63;
  const int c32 = lane & 31;
  const int h = lane >> 5;
  const bool hb = (h != 0);
  const int sub = wid >> 2;        // q-subtile (32 rows each)
  const int qr  = wid & 3;         // key quarter (1024 keys each)
  const int b = blockIdx.x & 3, qt = blockIdx.x >> 2;   // qt 0..63
  const int n0 = qt * 64;

  // Q fragments (dense 1KB loads)
  half8 qf[4];
  const _Float16* qfb = qfrag + (size_t)(b*128 + qt*2 + sub) * 2048;
  #pragma unroll
  for (int ks = 0; ks < 4; ++ks)
    qf[ks] = *(const half8*)(qfb + ks*512 + lane*8);

  const _Float16* kfb = kfrag + (size_t)(b*64 + qr*16) * 4096;
  const _Float16* vfb = vfrag + (size_t)(b*64 + qr*16) * 8192;

  f32x16 ctx[4];
  #pragma unroll
  for (int ct = 0; ct < 4; ++ct)
    #pragma unroll
    for (int r = 0; r < 16; ++r) ctx[ct][r] = 0.f;
  float run_m = -1e30f, run_l = 0.f;

  // ---- prologue: K(0), V(0); compute S(0); then prefetch K(1)
  half8 kf[2][4];
  #pragma unroll
  for (int mt = 0; mt < 2; ++mt)
    #pragma unroll
    for (int ks = 0; ks < 4; ++ks)
      kf[mt][ks] = *(const half8*)(kfb + (size_t)(mt*4 + ks)*512 + lane*8);

  half8 vA[2][4], vB[2][4];
  #pragma unroll
  for (int ms = 0; ms < 2; ++ms)
    #pragma unroll
    for (int ct = 0; ct < 4; ++ct) {
      vA[ms][ct] = *(const half8*)(vfb + (size_t)(ms*4 + ct)*512 + lane*8);
      vB[ms][ct] = *(const half8*)(vfb + (size_t)((ms+2)*4 + ct)*512 + lane*8);
    }

  f32x16 s[2];
  #pragma unroll
  for (int mt = 0; mt < 2; ++mt)
    #pragma unroll
    for (int r = 0; r < 16; ++r) s[mt][r] = 0.f;
  #pragma unroll
  for (int ks = 0; ks < 4; ++ks) {
    s[0] = __builtin_amdgcn_mfma_f32_32x32x16_f16(kf[0][ks], qf[ks], s[0], 0, 0, 0);
    s[1] = __builtin_amdgcn_mfma_f32_32x32x16_f16(kf[1][ks], qf[ks], s[1], 0, 0, 0);
  }
  // K(1) into kf (in place; QK^T(0) above already consumed K(0))
  #pragma unroll
  for (int mt = 0; mt < 2; ++mt)
    #pragma unroll
    for (int ks = 0; ks < 4; ++ks)
      kf[mt][ks] = *(const half8*)(kfb + (size_t)4096 + (size_t)(mt*4 + ks)*512 + lane*8);

  #pragma unroll 2
  for (int it = 0; it < 16; ++it) {
    // ---- softmax on s = S(it)  (column n = lane&31; partner = lane^32)
    float t8[8];
    #pragma unroll
    for (int r = 0; r < 8; ++r)
      t8[r] = fmaxf(fmaxf(s[0][r], s[0][r+8]), fmaxf(s[1][r], s[1][r+8]));
    #pragma unroll
    for (int off = 4; off > 0; off >>= 1)
      #pragma unroll
      for (int r = 0; r < off; ++r) t8[r] = fmaxf(t8[r], t8[r+off]);
    float tm = t8[0];
    float tmf = fmaxf(tm, __shfl_xor(tm, 32));
    if (!__all(tmf <= run_m + 8.f)) {
      float nm = fmaxf(run_m, tmf);
      float corr = fexp2(run_m - nm);
      run_m = nm;
      run_l *= corr;
      float cr[16];
      #pragma unroll
      for (int r = 0; r < 16; ++r) {
        int nr = (r & 3) + 8*(r >> 2) + 4*h;
        cr[r] = __shfl(corr, nr);
      }
      #pragma unroll
      for (int ct = 0; ct < 4; ++ct)
        #pragma unroll
        for (int r = 0; r < 16; ++r) ctx[ct][r] *= cr[r];
    }

    // ---- exp + pack fp16 + half-exchange via shfl_xor(32) -> PV A-frags
    float rs = 0.f;
    half8 pa4[4];
    #pragma unroll
    for (int mt = 0; mt < 2; ++mt) {
      uint32_t u[8];
      #pragma unroll
      for (int i = 0; i < 8; ++i) {
        float pa_ = fexp2(s[mt][2*i]   - run_m);
        float pb_ = fexp2(s[mt][2*i+1] - run_m);
        rs += pa_ + pb_;
        u[i] = __builtin_bit_cast(uint32_t, __builtin_amdgcn_cvt_pkrtz(pa_, pb_));
      }
      uint32_t t02 = __shfl_xor(hb ? u[0] : u[2], 32);
      uint32_t t13 = __shfl_xor(hb ? u[1] : u[3], 32);
      uint32_t t46 = __shfl_xor(hb ? u[4] : u[6], 32);
      uint32_t t57 = __shfl_xor(hb ? u[5] : u[7], 32);
      u32x4 w0 = { hb ? t02 : u[0], hb ? t13 : u[1],
                   hb ? u[2] : t02, hb ? u[3] : t13 };   // ms = 2*mt
      u32x4 w1 = { hb ? t46 : u[4], hb ? t57 : u[5],
                   hb ? u[6] : t46, hb ? u[7] : t57 };   // ms = 2*mt+1
      pa4[2*mt]   = __builtin_bit_cast(half8, w0);
      pa4[2*mt+1] = __builtin_bit_cast(half8, w1);
    }
    rs += __shfl_xor(rs, 32);

    // ---- QK^T(it+1): s consumed above; overwrite with next tile's scores.
    //      kf holds K(it+1), issued a full iteration ago.
    #pragma unroll
    for (int mt = 0; mt < 2; ++mt)
      #pragma unroll
      for (int r = 0; r < 16; ++r) s[mt][r] = 0.f;
    __builtin_amdgcn_s_setprio(1);
    #pragma unroll
    for (int ks = 0; ks < 4; ++ks) {
      s[0] = __builtin_amdgcn_mfma_f32_32x32x16_f16(kf[0][ks], qf[ks], s[0], 0, 0, 0);
      s[1] = __builtin_amdgcn_mfma_f32_32x32x16_f16(kf[1][ks], qf[ks], s[1], 0, 0, 0);
    }
    __builtin_amdgcn_s_setprio(0);

    // ---- issue K(it+2) (in place; kf just consumed)
    {
      const _Float16* kn = kfb + (size_t)((it + 2) & 15) * 4096;
      #pragma unroll
      for (int mt = 0; mt < 2; ++mt)
        #pragma unroll
        for (int ks = 0; ks < 4; ++ks)
          kf[mt][ks] = *(const half8*)(kn + (size_t)(mt*4 + ks)*512 + lane*8);
    }

    // ---- PV(it): ctx[n][c] += P[n][m] V[m][c]  (V issued a full iter ago)
    __builtin_amdgcn_s_setprio(1);
    #pragma unroll
    for (int ms = 0; ms < 2; ++ms)
      #pragma unroll
      for (int ct = 0; ct < 4; ++ct)
        ctx[ct] = __builtin_amdgcn_mfma_f32_32x32x16_f16(pa4[ms], vA[ms][ct], ctx[ct], 0, 0, 0);
    #pragma unroll
    for (int ms = 0; ms < 2; ++ms)
      #pragma unroll
      for (int ct = 0; ct < 4; ++ct)
        ctx[ct] = __builtin_amdgcn_mfma_f32_32x32x16_f16(pa4[ms+2], vB[ms][ct], ctx[ct], 0, 0, 0);
    __builtin_amdgcn_s_setprio(0);

    run_l += rs;

    // ---- issue V(it+1) (in place; vA/vB just consumed by PV)
    {
      const _Float16* vtn = vfb + (size_t)((it + 1) & 15) * 8192;
      #pragma unroll
      for (int ms = 0; ms < 2; ++ms)
        #pragma unroll
        for (int ct = 0; ct < 4; ++ct) {
          vA[ms][ct] = *(const half8*)(vtn + (size_t)(ms*4 + ct)*512 + lane*8);
          vB[ms][ct] = *(const half8*)(vtn + (size_t)((ms+2)*4 + ct)*512 + lane*8);
        }
    }
  }

  // ---- 4-way key merge per q-subtile (only synchronization in the kernel)
  if (qr != 0) {
    const int slot = sub*3 + (qr - 1);
    #pragma unroll
    for (int ct = 0; ct < 4; ++ct)
      #pragma unroll
      for (int r = 0; r < 16; ++r)
        ctxb[slot*4096 + (ct*16 + r)*64 + lane] = ctx[ct][r];
    if (h == 0) {
      statb[slot*64 + c32*2 + 0] = run_m;
      statb[slot*64 + c32*2 + 1] = run_l;
    }
  }
  __syncthreads();

  if (qr == 0) {
    float m_w[4], l_w[4];
    m_w[0] = run_m; l_w[0] = run_l;
    #pragma unroll
    for (int w = 1; w < 4; ++w) {
      const int slot = sub*3 + (w - 1);
      m_w[w] = statb[slot*64 + c32*2 + 0];
      l_w[w] = statb[slot*64 + c32*2 + 1];
    }
    float M = fmaxf(fmaxf(m_w[0], m_w[1]), fmaxf(m_w[2], m_w[3]));
    float sc[4], L = 0.f;
    #pragma unroll
    for (int w = 0; w < 4; ++w) { sc[w] = fexp2(m_w[w] - M); L += l_w[w]*sc[w]; }
    float inv = 1.0f / L;
    float a0[16], a1[16], a2[16], a3[16], ai[16];
    #pragma unroll
    for (int r = 0; r < 16; ++r) {
      int nr = (r & 3) + 8*(r >> 2) + 4*h;
      a0[r] = __shfl(sc[0], nr); a1[r] = __shfl(sc[1], nr);
      a2[r] = __shfl(sc[2], nr); a3[r] = __shfl(sc[3], nr);
      ai[r] = __shfl(inv, nr);
    }
    #pragma unroll
    for (int ct = 0; ct < 4; ++ct)
      #pragma unroll
      for (int r = 0; r < 16; ++r) {
        int nr = (r & 3) + 8*(r >> 2) + 4*h;
        float vmrg = ctx[ct][r]*a0[r]
                   + ctxb[(sub*3 + 0)*4096 + (ct*16 + r)*64 + lane]*a1[r]
                   + ctxb[(sub*3 + 1)*4096 + (ct*16 + r)*64 + lane]*a2[r]
                   + ctxb[(sub*3 + 2)*4096 + (ct*16 + r)*64 + lane]*a3[r];
        ctxw[(sub*32 + nr)*132 + ct*32 + c32] = vmrg * ai[r];
      }
  }
  __syncthreads();

  // ---- residual add + store: thread t -> channel c = t>>2, 16 n each
  {
    const int c  = tid >> 2;
    const int nl = (tid & 3) * 16;
    const float* xr   = x   + (size_t)(b*CC + c)*NN + n0 + nl;
    float*       orow = out + (size_t)(b*CC + c)*NN + n0 + nl;
    #pragma unroll
    for (int i4 = 0; i4 < 4; ++i4) {
      float4 xv = *(const float4*)(xr + i4*4);
      float4 o;
      o.x = xv.x + ctxw[(nl + i4*4 + 0)*132 + c];
      o.y = xv.y + ctxw[(nl + i4*4 + 1)*132 + c];
      o.z = xv.z + ctxw[(nl + i4*4 + 2)*132 + c];
      o.w = xv.w + ctxw[(nl + i4*4 + 3)*132 + c];
      *(float4*)(orow + i4*4) = o;
    }
  }
}

// ---------------------------------------------------------------------------
extern "C" void kernel_launch(void* const* d_in, const int* in_sizes, int n_in,
                              void* d_out, int out_size, void* d_ws, size_t ws_size,
                              hipStream_t stream) {
  const float* x  = (const float*)d_in[0];
  const float* Wq = (const float*)d_in[1];
  const float* bq = (const float*)d_in[2];
  const float* Wk = (const float*)d_in[3];
  const float* bk = (const float*)d_in[4];
  const float* Wv = (const float*)d_in[5];
  const float* bv = (const float*)d_in[6];
  float* out = (float*)d_out;

  _Float16* qfrag = (_Float16*)d_ws;                       // 2MB
  _Float16* kfrag = qfrag + (size_t)BB * 128 * 2048;       // 2MB
  _Float16* vfrag = kfrag + (size_t)BB * 64 * 4096;        // 4MB

  proj_kernel<<<dim3(BB * (NN/64)), dim3(256), 0, stream>>>(
      x, Wq, bq, Wk, bk, Wv, bv, qfrag, kfrag, vfrag);
  attn_kernel<<<dim3(BB * (NN/64)), dim3(512), 0, stream>>>(
      x, qfrag, kfrag, vfrag, out);
}